// Round 24
// baseline (71.496 us; speedup 1.0000x reference)
//
#include <hip/hip_runtime.h>
#include <math.h>

#define SS 4096
#define EE 1024
#define HH 16
#define DD 64
#define RMAX 128
#define NCOL 128
#define NRED 8
#define NPROJ 768  // 2 rt * (3 m * 4 kc * 32 etiles32); both operands in LDS
#define NREDB 96   // d1b reduce blocks
#define NBG 64
#define NVS 16
#define NATT 256

// ---------------------------------------------------------------------------
// ws float offsets. LESSONS: (r9/r10) no 4KB-strided ws reads; (r3) no BULK
// global atomics; (r5/r7) no software grid barriers; (r13) no shallow-flight
// staging; (r19) not W-volume-bound; (r20) k-contention real (stagger -5us);
// (r21) not ILP-depth-bound; (r22/r23) FETCH halved / LDS-W deep-staged:
// time flat ~33us => global-x compute paths stay latency-bound. (r24) BOTH
// operands in LDS, x as k-pairs (1 ds_read_b64-equiv per 2k) + uniform b128
// W broadcasts => FMA-bound by issue arithmetic. xT eliminated.
//   meta   int[0..1]      (s0, L)
//   sumx   [EE]           @64
//   bgA    [EE]           @1088
//   betap  [HH][DD]       @2112   (atomic; zeroed by D1 block 0)
//   alphap [HH]           @3136
//   vsumh  [HH][DD]       @3200
//   partT  [EE][NCOL]     @8192
//   qh     [HH][RMAX][DD] @270336 (rows >=L zeroed by d1b)
//   kTh    [HH][DD][RMAX] @401408 (cols >=L zeroed by d1b)
//   vh     [HH][RMAX][DD] @532480 (rows >=L zeroed by d1b)
//   ypart  [12][RMAX][EE] @663552 (proj quadrant partials, 6 MB)
// ---------------------------------------------------------------------------
#define OFF_SUMX  64
#define OFF_BGA   1088
#define OFF_BETA  2112
#define OFF_ALPHA 3136
#define OFF_VSUM  3200
#define OFF_PART  8192
#define OFF_QH    270336
#define OFF_KTH   (OFF_QH + HH * RMAX * DD)
#define OFF_VH    (OFF_KTH + HH * DD * RMAX)
#define OFF_YP    (OFF_VH + HH * RMAX * DD)

__device__ __forceinline__ void seg_scan(const int* __restrict__ seg,
                                         const int* __restrict__ posp,
                                         int* sh, int& s0, int& L) {
    if (threadIdx.x == 0) { sh[0] = SS; sh[1] = -1; }
    __syncthreads();
    int sid = seg[posp[0]];
    int lmin = SS, lmax = -1;
    for (int i = threadIdx.x; i < SS; i += 256)
        if (seg[i] == sid) { lmin = min(lmin, i); lmax = max(lmax, i); }
#pragma unroll
    for (int off = 32; off; off >>= 1) {
        lmin = min(lmin, __shfl_xor(lmin, off));
        lmax = max(lmax, __shfl_xor(lmax, off));
    }
    if ((threadIdx.x & 63) == 0) { atomicMin(&sh[0], lmin); atomicMax(&sh[1], lmax); }
    __syncthreads();
    s0 = sh[0];
    L  = sh[1] - sh[0] + 1;
    if (L > RMAX) L = RMAX;
    if (L < 1)    L = 1;
}

// -------- D0: colsum -> partT (128 blk) || seg scan -> meta (1 blk) --------
__global__ __launch_bounds__(256) void d0_kernel(
    const float* __restrict__ x, const int* __restrict__ seg,
    const int* __restrict__ posp, float* __restrict__ ws) {
    int bid = blockIdx.x, tid = threadIdx.x;
    if (bid < NCOL) {
        float* partT = ws + OFF_PART;
        int r0 = bid * (SS / NCOL);
        const float4* x4 = (const float4*)x;
        float4 a = make_float4(0.f, 0.f, 0.f, 0.f);
#pragma unroll 8
        for (int r = 0; r < SS / NCOL; ++r) {
            float4 v = x4[(size_t)(r0 + r) * 256 + tid];
            a.x += v.x; a.y += v.y; a.z += v.z; a.w += v.w;
        }
        partT[(size_t)(4 * tid + 0) * NCOL + bid] = a.x;
        partT[(size_t)(4 * tid + 1) * NCOL + bid] = a.y;
        partT[(size_t)(4 * tid + 2) * NCOL + bid] = a.z;
        partT[(size_t)(4 * tid + 3) * NCOL + bid] = a.w;
        return;
    }
    __shared__ int sh[2];
    int s0, L;
    seg_scan(seg, posp, sh, s0, L);
    if (tid == 0) { ((int*)ws)[0] = s0; ((int*)ws)[1] = L; }
}

// -------- D1: sumx reduce + zero accum (8 blk) || QKV proj partials (768) ----
// Block = (rt, m, kc, 32-e tile). Per 128-k round: x chunk transposed into
// LDS as k-PAIRS (xs[k2][r][2]) + W chunk [k][e] in LDS. Compute per 2k:
// one float2 LDS read (contiguous, conflict-free) + 4 uniform b128 broadcasts
// + 16 FMA => FMA-bound. Partials -> ypart[m*4+kc][r][e].
__global__ __launch_bounds__(256) void d1_kernel(
    const float* __restrict__ x,
    const float* __restrict__ Wq, const float* __restrict__ Wk,
    const float* __restrict__ Wv, float* __restrict__ ws) {
    int bid = blockIdx.x, tid = threadIdx.x;
    if (bid < NRED) {
        if (bid == 0) {   // zero betap+alphap atomic accumulators
            for (int i = tid; i < 1088; i += 256) (ws + OFF_BETA)[i] = 0.f;
        }
        const float* partT = ws + OFF_PART;
        int e  = bid * 128 + (tid >> 1);
        int c0 = (tid & 1) * 64;
        const float4* p4 = (const float4*)(partT + (size_t)e * NCOL + c0);
        float4 s4 = make_float4(0.f, 0.f, 0.f, 0.f);
#pragma unroll
        for (int i = 0; i < 16; ++i) {
            float4 v = p4[i];
            s4.x += v.x; s4.y += v.y; s4.z += v.z; s4.w += v.w;
        }
        float s = s4.x + s4.y + s4.z + s4.w;
        s += __shfl_xor(s, 1);
        if ((tid & 1) == 0) (ws + OFF_SUMX)[e] = s;
        return;
    }
    __shared__ float xs[64 * 130];    // [k2][r*2+parity]  33.3 KB
    __shared__ float wsm[128 * 36];   // [k][e]            18.4 KB
    int s0 = ((const int*)ws)[0];
    int L  = ((const int*)ws)[1];
    int Lp = (L + 63) & ~63;
    int pid = bid - NRED;             // 0..767
    int rt  = (pid >= 384) ? 1 : 0;   // high bit: XCD pairing (384%8==0)
    int rem = pid - rt * 384;         // 0..383
    int m   = rem >> 7;               // 0..2
    int rem2 = rem & 127;
    int kc  = rem2 >> 5;              // 0..3
    int et  = rem2 & 31;              // 0..31
    int r0  = rt * 64;
    if (r0 >= Lp) return;
    const float* W = (m == 0) ? Wq : ((m == 1) ? Wk : Wv);
    int e0t = et * 32;
    int lane = tid & 63;
    int w4   = tid >> 6;
    int eo   = w4 * 8;                // wave's 8 e (local)
    float a0 = 0.f, a1 = 0.f, a2 = 0.f, a3 = 0.f;
    float a4 = 0.f, a5 = 0.f, a6 = 0.f, a7 = 0.f;

    for (int rr = 0; rr < 2; ++rr) {
        int k0 = kc * 256 + rr * 128;
        __syncthreads();
        for (int idx = tid; idx < 2048; idx += 256) {   // xs: 64 r x 32 k4
            int k4 = idx & 31, r = idx >> 5;
            float4 v = make_float4(0.f, 0.f, 0.f, 0.f);
            if (r0 + r < L)
                v = *(const float4*)(x + (size_t)(s0 + r0 + r) * EE + k0 + k4 * 4);
            int kb = k4 * 2;                             // k-pair base
            xs[(kb + 0) * 130 + r * 2 + 0] = v.x;
            xs[(kb + 0) * 130 + r * 2 + 1] = v.y;
            xs[(kb + 1) * 130 + r * 2 + 0] = v.z;
            xs[(kb + 1) * 130 + r * 2 + 1] = v.w;
        }
        for (int idx = tid; idx < 1024; idx += 256) {   // wsm: 32 e x 32 k4
            int k4 = idx & 31, e = idx >> 5;
            float4 v = *(const float4*)(W + (size_t)(e0t + e) * EE + k0 + k4 * 4);
            wsm[(k4 * 4 + 0) * 36 + e] = v.x;
            wsm[(k4 * 4 + 1) * 36 + e] = v.y;
            wsm[(k4 * 4 + 2) * 36 + e] = v.z;
            wsm[(k4 * 4 + 3) * 36 + e] = v.w;
        }
        __syncthreads();
#pragma unroll 8
        for (int k2 = 0; k2 < 64; ++k2) {
            float2 xr = *(const float2*)&xs[k2 * 130 + lane * 2];
            const float4* wA = (const float4*)&wsm[(2 * k2 + 0) * 36 + eo];
            const float4* wB = (const float4*)&wsm[(2 * k2 + 1) * 36 + eo];
            float4 wa0 = wA[0], wa1 = wA[1];
            float4 wb0 = wB[0], wb1 = wB[1];
            a0 += wa0.x * xr.x + wb0.x * xr.y;
            a1 += wa0.y * xr.x + wb0.y * xr.y;
            a2 += wa0.z * xr.x + wb0.z * xr.y;
            a3 += wa0.w * xr.x + wb0.w * xr.y;
            a4 += wa1.x * xr.x + wb1.x * xr.y;
            a5 += wa1.y * xr.x + wb1.y * xr.y;
            a6 += wa1.z * xr.x + wb1.z * xr.y;
            a7 += wa1.w * xr.x + wb1.w * xr.y;
        }
    }
    // partial store: ypart[m*4+kc][r0+lane][e0t+eo .. +8)
    float* dst = ws + OFF_YP + ((size_t)(m * 4 + kc) * RMAX + (r0 + lane)) * EE
               + e0t + eo;
    *(float4*)(dst)     = make_float4(a0, a1, a2, a3);
    *(float4*)(dst + 4) = make_float4(a4, a5, a6, a7);
}

// -------- D1b: reduce ypart -> qh / kTh / vh (+bias, r<L gate). 96 blk -----
__global__ __launch_bounds__(256) void d1b_kernel(
    const float* __restrict__ bq, const float* __restrict__ bk,
    const float* __restrict__ bv, float* __restrict__ ws) {
    int bid = blockIdx.x, tid = threadIdx.x;
    int L = ((const int*)ws)[1];
    int m  = bid / 32;
    int rg = bid % 32;                // 4 rows each
    const float* b = (m == 0) ? bq : ((m == 1) ? bk : bv);
    float* qh  = ws + OFF_QH;
    float* kTh = ws + OFF_KTH;
    float* vh  = ws + OFF_VH;
    float4 bb = ((const float4*)b)[tid];
    int e = tid * 4;
    int h = e >> 6, d = e & 63;
#pragma unroll
    for (int rr = 0; rr < 4; ++rr) {
        int r = rg * 4 + rr;
        const float4* y0 = (const float4*)(ws + OFF_YP + ((size_t)(m * 4 + 0) * RMAX + r) * EE);
        const float4* y1 = (const float4*)(ws + OFF_YP + ((size_t)(m * 4 + 1) * RMAX + r) * EE);
        const float4* y2 = (const float4*)(ws + OFF_YP + ((size_t)(m * 4 + 2) * RMAX + r) * EE);
        const float4* y3 = (const float4*)(ws + OFF_YP + ((size_t)(m * 4 + 3) * RMAX + r) * EE);
        float4 s0 = y0[tid], s1 = y1[tid], s2 = y2[tid], s3 = y3[tid];
        float o0 = s0.x + s1.x + s2.x + s3.x + bb.x;
        float o1 = s0.y + s1.y + s2.y + s3.y + bb.y;
        float o2 = s0.z + s1.z + s2.z + s3.z + bb.z;
        float o3 = s0.w + s1.w + s2.w + s3.w + bb.w;
        if (r >= L) { o0 = 0.f; o1 = 0.f; o2 = 0.f; o3 = 0.f; }
        if (m == 1) {
            kTh[(size_t)(h * DD + d + 0) * RMAX + r] = o0;
            kTh[(size_t)(h * DD + d + 1) * RMAX + r] = o1;
            kTh[(size_t)(h * DD + d + 2) * RMAX + r] = o2;
            kTh[(size_t)(h * DD + d + 3) * RMAX + r] = o3;
        } else {
            float* y = (m == 0) ? qh : vh;
            *(float4*)&y[((size_t)h * RMAX + r) * DD + d] = make_float4(o0, o1, o2, o3);
        }
    }
}

// -------- D2: bgA (64) || vsumh (16) || attention, 1 wave per (r,h) (256) ----
__global__ __launch_bounds__(256) void d2_kernel(
    const float* __restrict__ Wv, const float* __restrict__ bv,
    float* __restrict__ ws) {
    __shared__ float qS[4 * 64];
    __shared__ float wS[4 * 128];
    __shared__ float vp_[4][64];
    const float* sumx = ws + OFF_SUMX;
    float* bgA    = ws + OFF_BGA;
    float* betap  = ws + OFF_BETA;
    float* alphap = ws + OFF_ALPHA;
    float* vsumh  = ws + OFF_VSUM;
    const float* qh  = ws + OFF_QH;
    const float* kTh = ws + OFF_KTH;
    const float* vh  = ws + OFF_VH;

    int bid = blockIdx.x, tid = threadIdx.x;
    int lane = tid & 63, wave = tid >> 6;
    int L  = ((const int*)ws)[1];
    int Lp = (L + 63) & ~63;

    if (bid < NBG) {
        int e = bid * 16 + (tid >> 4);
        int j = tid & 15;
        const float4* wr  = (const float4*)(Wv + (size_t)e * EE);
        const float4* sx4 = (const float4*)sumx;
        float p = 0.f;
#pragma unroll
        for (int jj = 0; jj < 16; ++jj) {
            float4 w = wr[jj * 16 + j], z = sx4[jj * 16 + j];
            p += w.x * z.x + w.y * z.y + w.z * z.z + w.w * z.w;
        }
        p += __shfl_xor(p, 8);
        p += __shfl_xor(p, 4);
        p += __shfl_xor(p, 2);
        p += __shfl_xor(p, 1);
        if (j == 0) bgA[e] = p + (float)SS * bv[e];
        return;
    }
    if (bid < NBG + NVS) {
        int h = bid - NBG;
        float s = 0.f;
        for (int t = wave; t < Lp; t += 4)
            s += vh[((size_t)h * RMAX + t) * DD + lane];
        vp_[wave][lane] = s;
        __syncthreads();
        if (wave == 0)
            vsumh[h * DD + lane] = vp_[0][lane] + vp_[1][lane]
                                 + vp_[2][lane] + vp_[3][lane];
        return;
    }

    int aid = bid - NBG - NVS;
    int gidbase = aid * 4 + wave;
    int pairs = L * HH;
    float* qSw = qS + wave * 64;
    float* wSw = wS + wave * 128;
    for (int wg = gidbase; wg < pairs; wg += NATT * 4) {
        int h = wg & (HH - 1);
        int r = wg >> 4;
        qSw[lane] = qh[((size_t)h * RMAX + r) * DD + lane];
        float s0 = 0.f, s1 = 0.f;
#pragma unroll
        for (int d = 0; d < 64; ++d) {
            float qd = qSw[d];
            const float* kr = kTh + (size_t)(h * DD + d) * RMAX;
            s0 += qd * kr[lane];
            s1 += qd * kr[64 + lane];
        }
        float v0 = (lane < L)      ? s0 : -3.0e38f;
        float v1 = (64 + lane < L) ? s1 : -3.0e38f;
        float m = fmaxf(0.f, fmaxf(v0, v1));
#pragma unroll
        for (int off = 32; off; off >>= 1) m = fmaxf(m, __shfl_xor(m, off));
        float w0 = (lane < L)      ? __expf(s0 - m) : 0.f;
        float w1 = (64 + lane < L) ? __expf(s1 - m) : 0.f;
        float Zl = w0 + w1;
#pragma unroll
        for (int off = 32; off; off >>= 1) Zl += __shfl_xor(Zl, off);
        float em = __expf(-m);
        float Z  = Zl + (float)(SS - L) * em;
        wSw[lane]      = w0;
        wSw[64 + lane] = w1;
        float acc = 0.f;
#pragma unroll 16
        for (int t = 0; t < Lp; ++t)
            acc += wSw[t] * vh[((size_t)h * RMAX + t) * DD + lane];
        float invZ = 1.0f / Z;
        atomicAdd(&betap[h * DD + lane], acc * invZ);
        if (lane == 0) atomicAdd(&alphap[h], em * invZ);
    }
}

// -------- D3: out[e] = bo[e] + Wo[e,:].(beta + alpha o (bgA - vsumh)) / L ----
__global__ __launch_bounds__(256) void d3_kernel(
    const float* __restrict__ Wo, const float* __restrict__ bo,
    const float* __restrict__ ws, float* __restrict__ out) {
    __shared__ float z[EE];
    int tid = threadIdx.x;
    int lane = tid & 63, wave = tid >> 6;
    int L = ((const int*)ws)[1];

    {
        int h = tid >> 4;
        float4 beta = ((const float4*)(ws + OFF_BETA))[tid];
        float  a    = (ws + OFF_ALPHA)[h];
        float4 g    = ((const float4*)(ws + OFF_BGA))[tid];
        float4 vs   = ((const float4*)(ws + OFF_VSUM))[tid];
        ((float4*)z)[tid] = make_float4(beta.x + a * (g.x - vs.x),
                                        beta.y + a * (g.y - vs.y),
                                        beta.z + a * (g.z - vs.z),
                                        beta.w + a * (g.w - vs.w));
    }
    __syncthreads();

    int e = blockIdx.x * 4 + wave;
    const float4* wr = (const float4*)(Wo + (size_t)e * EE);
    const float4* z4 = (const float4*)z;
    float p = 0.f;
#pragma unroll
    for (int it = 0; it < 4; ++it) {
        float4 w = wr[it * 64 + lane], zz = z4[it * 64 + lane];
        p += w.x * zz.x + w.y * zz.y + w.z * zz.z + w.w * zz.w;
    }
#pragma unroll
    for (int off = 32; off; off >>= 1) p += __shfl_xor(p, off);
    if (lane == 0) out[e] = bo[e] + p / (float)L;
}

extern "C" void kernel_launch(void* const* d_in, const int* in_sizes, int n_in,
                              void* d_out, int out_size, void* d_ws, size_t ws_size,
                              hipStream_t stream) {
    const float* x   = (const float*)d_in[0];
    const float* Wq  = (const float*)d_in[1];
    const float* bq  = (const float*)d_in[2];
    const float* Wk  = (const float*)d_in[3];
    const float* bk  = (const float*)d_in[4];
    const float* Wv  = (const float*)d_in[5];
    const float* bv  = (const float*)d_in[6];
    const float* Wo  = (const float*)d_in[7];
    const float* bo  = (const float*)d_in[8];
    const int*   seg = (const int*)d_in[9];
    const int*   pos = (const int*)d_in[10];
    float*       out = (float*)d_out;
    float*       ws  = (float*)d_ws;

    d0_kernel<<<NCOL + 1, 256, 0, stream>>>(x, seg, pos, ws);
    d1_kernel<<<NRED + NPROJ, 256, 0, stream>>>(x, Wq, Wk, Wv, ws);
    d1b_kernel<<<NREDB, 256, 0, stream>>>(bq, bk, bv, ws);
    d2_kernel<<<NBG + NVS + NATT, 256, 0, stream>>>(Wv, bv, ws);
    d3_kernel<<<EE / 4, 256, 0, stream>>>(Wo, bo, ws, out);
}